// Round 5
// baseline (91.272 us; speedup 1.0000x reference)
//
#include <hip/hip_runtime.h>
#include <math.h>

#define NUM_CLASSES 80
#define REG_MAX 16
#define NCH 144            // 4*REG_MAX + NUM_CLASSES
#define A_TOT 8400         // 80*80 + 40*40 + 20*20
#define BATCH 32
#define MAX_DET 300
#define CONF_THR 0.25f
#define IOU_THR 0.7f
#define MAX_WH 7680.0f
#define CAND_CAP 1024
#define NBINS 1024
#define MASK_W 10          // ceil(300/32)

// ---------------------------------------------------------------------------
// Kernel 1: scores + argmax class ONLY (class channels 64..143). (= R4)
// ---------------------------------------------------------------------------
__global__ __launch_bounds__(256) void score_kernel(
    const float* __restrict__ p3, const float* __restrict__ p4,
    const float* __restrict__ p5,
    float* __restrict__ scores, int* __restrict__ clsArr)
{
    const int t = blockIdx.x * 256 + threadIdx.x;
    const int g = t >> 2;                  // anchor id in [0, 268800)
    const int p = t & 3;
    const int b = g / A_TOT;
    const int a = g - b * A_TOT;

    const float* src;
    if (a < 6400)      src = p3 + ((size_t)b * 6400 + a) * NCH;
    else if (a < 8000) src = p4 + ((size_t)b * 1600 + (a - 6400)) * NCH;
    else               src = p5 + ((size_t)b * 400  + (a - 8000)) * NCH;

    const float4* s4 = (const float4*)src;
    float best = -INFINITY;
    int cbest = p * 4;
    #pragma unroll
    for (int q = 0; q < 5; ++q) {
        float4 c4 = s4[16 + q * 4 + p];    // coalesced: p spans one 64B line
        int c = q * 16 + p * 4;
        if (c4.x > best) { best = c4.x; cbest = c + 0; }
        if (c4.y > best) { best = c4.y; cbest = c + 1; }
        if (c4.z > best) { best = c4.z; cbest = c + 2; }
        if (c4.w > best) { best = c4.w; cbest = c + 3; }
    }
    #pragma unroll
    for (int d = 1; d < 4; d <<= 1) {
        float ob = __shfl_xor(best, d, 64);
        int   oc = __shfl_xor(cbest, d, 64);
        if (ob > best || (ob == best && oc < cbest)) { best = ob; cbest = oc; }
    }

    if (p == 0) {
        float sig = 1.0f / (1.0f + expf(-best));
        scores[g] = (sig > CONF_THR) ? sig : 0.0f;
        clsArr[g] = cbest;
    }
}

// ---------------------------------------------------------------------------
// Kernel 2 (R5): per-batch top-300 + DFL decode (survivors) + IoU + greedy
// NMS. One block (1024 thr)/batch. Phase F rewritten word-pipelined.
// ---------------------------------------------------------------------------
__global__ __launch_bounds__(1024) void nms_kernel(
    const float* __restrict__ p3, const float* __restrict__ p4,
    const float* __restrict__ p5,
    const float* __restrict__ scores, const int* __restrict__ clsArr,
    float* __restrict__ out)
{
    __shared__ unsigned hist[NBINS];
    __shared__ unsigned wtot[16];
    __shared__ unsigned woff[16];
    __shared__ unsigned long long cand[CAND_CAP];
    __shared__ unsigned long long sortedK[MAX_DET];
    __shared__ float4 cbox4[MAX_DET];
    __shared__ float4 obox4[MAX_DET];
    __shared__ float oarea[MAX_DET];
    __shared__ float tops[MAX_DET];
    __shared__ float tcls[MAX_DET];
    __shared__ unsigned mask[MASK_W][MAX_DET];
    __shared__ unsigned keepW[MASK_W];
    __shared__ int bstar, cnt;

    const int b = blockIdx.x;
    const int tid = threadIdx.x;
    const int lane = tid & 63;
    const int wv = tid >> 6;
    const float* sc = scores + (size_t)b * A_TOT;
    const int* cl = clsArr + (size_t)b * A_TOT;

    // --- prologue -----------------------------------------------------------
    hist[tid] = 0;
    cand[tid] = 0ULL;                      // CAND_CAP == 1024 == blockDim
    if (tid < MAX_DET) sortedK[tid] = 0ULL;
    if (tid == 0) { cnt = 0; bstar = 0; }
    __syncthreads();

    // --- Phase A: scores -> regs; histogram of nonzero ----------------------
    float sreg[9];
    int breg[9];
    #pragma unroll
    for (int k = 0; k < 9; ++k) {
        int i = tid + k * 1024;
        float s = (i < A_TOT) ? sc[i] : 0.0f;
        sreg[k] = s;
        if (s > 0.0f) {
            int bin = min((int)(s * (float)NBINS), NBINS - 1);
            breg[k] = bin;
            atomicAdd(&hist[bin], 1u);
        } else breg[k] = -1;
    }
    __syncthreads();

    // --- suffix scan (wave shuffle + 16 wave totals) ------------------------
    unsigned v = hist[tid];
    #pragma unroll
    for (int d = 1; d < 64; d <<= 1) {
        unsigned o = __shfl_down(v, d, 64);
        if (lane + d < 64) v += o;
    }
    if (lane == 0) wtot[wv] = v;
    __syncthreads();
    if (tid < 16) {
        unsigned u = wtot[tid];
        unsigned t2 = u;
        #pragma unroll
        for (int d = 1; d < 16; d <<= 1) {
            unsigned o = __shfl_down(t2, d, 64);
            if (tid + d < 16) t2 += o;
        }
        woff[tid] = t2 - u;
    }
    __syncthreads();
    unsigned suff = v + woff[wv];
    hist[tid] = suff;
    __syncthreads();

    if (hist[tid] >= MAX_DET && (tid == NBINS - 1 || hist[tid + 1] < MAX_DET))
        bstar = tid;
    __syncthreads();
    const int bs = bstar;

    // --- Phase B: compact candidates from registers -------------------------
    #pragma unroll
    for (int k = 0; k < 9; ++k) {
        if (breg[k] >= bs && breg[k] >= 0) {
            int i = tid + k * 1024;
            int pos = atomicAdd(&cnt, 1);
            if (pos < CAND_CAP) {
                unsigned sb = __float_as_uint(sreg[k]);
                cand[pos] = ((unsigned long long)sb << 32) |
                            (unsigned long long)(0xFFFFFFFFu - (unsigned)i);
            }
        }
    }
    __syncthreads();

    // --- Phase C: rank-by-count ---------------------------------------------
    const int n = min(cnt, CAND_CAP);
    {
        unsigned long long mykey = cand[tid];
        if (mykey != 0ULL) {
            int r = 0;
            #pragma unroll 8
            for (int j = 0; j < n; ++j) r += (cand[j] > mykey) ? 1 : 0;
            if (r < MAX_DET) sortedK[r] = mykey;
        }
    }
    __syncthreads();

    // --- Phase D: unpack + DFL box decode for survivors (4 thr/anchor) ------
    const int gbase = lane & ~3;
    #pragma unroll
    for (int sweep = 0; sweep < 2; ++sweep) {
        int det = sweep * 256 + (tid >> 2);
        int p = tid & 3;
        unsigned long long key = (det < MAX_DET) ? sortedK[det] : 0ULL;
        float distp = 0.0f;
        unsigned i = 0xFFFFFFFFu - (unsigned)(key & 0xFFFFFFFFull);

        if (key != 0ULL) {
            const float* rowp;
            if (i < 6400)      rowp = p3 + ((size_t)b * 6400 + i) * NCH;
            else if (i < 8000) rowp = p4 + ((size_t)b * 1600 + (i - 6400)) * NCH;
            else               rowp = p5 + ((size_t)b * 400  + (i - 8000)) * NCH;
            const float4* s4 = (const float4*)rowp;
            float vv[16];
            float4 r0 = s4[p * 4 + 0];
            float4 r1 = s4[p * 4 + 1];
            float4 r2 = s4[p * 4 + 2];
            float4 r3 = s4[p * 4 + 3];
            vv[0]=r0.x; vv[1]=r0.y; vv[2]=r0.z; vv[3]=r0.w;
            vv[4]=r1.x; vv[5]=r1.y; vv[6]=r1.z; vv[7]=r1.w;
            vv[8]=r2.x; vv[9]=r2.y; vv[10]=r2.z; vv[11]=r2.w;
            vv[12]=r3.x; vv[13]=r3.y; vv[14]=r3.z; vv[15]=r3.w;
            float m = vv[0];
            #pragma unroll
            for (int k = 1; k < 16; ++k) m = fmaxf(m, vv[k]);
            float ssum = 0.0f, wsum = 0.0f;
            #pragma unroll
            for (int k = 0; k < 16; ++k) {
                float e = expf(vv[k] - m);
                ssum += e;
                wsum += e * (float)k;
            }
            distp = wsum / ssum;
        }
        float d0 = __shfl(distp, gbase + 0, 64);
        float d1 = __shfl(distp, gbase + 1, 64);
        float d2 = __shfl(distp, gbase + 2, 64);
        float d3 = __shfl(distp, gbase + 3, 64);

        if (det < MAX_DET && p == 0) {
            float s = __uint_as_float((unsigned)(key >> 32));
            tops[det] = s;
            float4 bb = make_float4(0.f, 0.f, 0.f, 0.f);
            float4 ob = bb;
            float cf = 0.0f;
            if (key != 0ULL) {
                int gyi, gxi; float strd;
                if (i < 6400)      { gyi = i / 80; gxi = i - gyi * 80; strd = 8.0f; }
                else if (i < 8000) { int li = i - 6400; gyi = li / 40; gxi = li - gyi * 40; strd = 16.0f; }
                else               { int li = i - 8000; gyi = li / 20; gxi = li - gyi * 20; strd = 32.0f; }
                float gx = (float)gxi + 0.5f;
                float gy = (float)gyi + 0.5f;
                float x1 = gx - d0, y1 = gy - d1;
                float x2 = gx + d2, y2 = gy + d3;
                float cx = ((x1 + x2) * 0.5f) * strd;
                float cy = ((y1 + y2) * 0.5f) * strd;
                float bw = (x2 - x1) * strd;
                float bh = (y2 - y1) * strd;
                float hx = bw * 0.5f, hy = bh * 0.5f;
                bb = make_float4(cx - hx, cy - hy, cx + hx, cy + hy);
                cf = (float)cl[i];
                float off = cf * MAX_WH;
                ob = make_float4(bb.x + off, bb.y + off, bb.z + off, bb.w + off);
            }
            cbox4[det] = bb;
            obox4[det] = ob;
            tcls[det] = cf;
            oarea[det] = (ob.z - ob.x) * (ob.w - ob.y);
        }
    }
    __syncthreads();

    // --- Phase E: 300x300 IoU > thr bitmask ---------------------------------
    for (int task = tid; task < MASK_W * MAX_DET; task += 1024) {
        int w = task / MAX_DET;
        int i = task - w * MAX_DET;
        float4 a = obox4[i];
        float aa = oarea[i];
        unsigned bits = 0;
        int j0 = w * 32;
        int jend = min(32, MAX_DET - j0);
        for (int jj = 0; jj < jend; ++jj) {
            int j = j0 + jj;
            float4 bo = obox4[j];
            float ab = oarea[j];
            float lx = fmaxf(a.x, bo.x), ly = fmaxf(a.y, bo.y);
            float rx = fminf(a.z, bo.z), ry = fminf(a.w, bo.w);
            float iw = fmaxf(rx - lx, 0.0f), ih = fmaxf(ry - ly, 0.0f);
            float inter = iw * ih;
            float iou = inter / (aa + ab - inter + 1e-7f);
            if (iou > IOU_THR) bits |= (1u << jj);
        }
        mask[w][i] = bits;
    }
    __syncthreads();

    // --- Phase F (R5): word-pipelined greedy scan (wave 0) -------------------
    // suppcur = suppression word for the current 32-box word, uniform in regs;
    // one shfl per word; mask rows + tops prefetched depth-2.
    if (tid < 64) {
        unsigned supp = 0u;                // lane w<MASK_W: word w of suppressed
        unsigned kw = 0u;                  // packed keep bits, current word
        unsigned suppcur = 0u;
        unsigned ml0 = (tid < MASK_W) ? mask[tid][0] : 0u;
        unsigned ml1 = (tid < MASK_W) ? mask[tid][1] : 0u;
        unsigned mu0 = mask[0][0];
        unsigned mu1 = mask[0][1];
        float    ts0 = tops[0];
        float    ts1 = tops[1];
        for (int i = 0; i < MAX_DET; ++i) {
            unsigned mlc = ml0; ml0 = ml1;
            unsigned muc = mu0; mu0 = mu1;
            float    tsc = ts0; ts0 = ts1;
            int ip = i + 2;
            if (ip < MAX_DET) {
                ml1 = (tid < MASK_W) ? mask[tid][ip] : 0u;
                mu1 = mask[ip >> 5][ip];
                ts1 = tops[ip];
            } else { ml1 = 0u; mu1 = 0u; ts1 = 0.0f; }

            if ((i & 31) == 0 && i > 0) {
                int pw = (i >> 5) - 1;
                if (tid == 0) keepW[pw] = kw;
                kw = 0u;
                suppcur = __shfl(supp, i >> 5, 64);
            }
            bool suppressed = (suppcur >> (i & 31)) & 1u;
            bool ki = (tsc > 0.0f) && !suppressed;     // uniform
            if (ki) {
                suppcur |= muc;
                if (tid < MASK_W) supp |= mlc;
                kw |= 1u << (i & 31);
            }
        }
        if (tid == 0) keepW[MASK_W - 1] = kw;
    }
    __syncthreads();

    // --- Phase G: write output [cbox(4), score, cls], zero if not kept ------
    float* ob = out + (size_t)b * MAX_DET * 6;
    for (int e = tid; e < MAX_DET * 6; e += 1024) {
        int i = e / 6, c = e - (e / 6) * 6;
        float val = 0.0f;
        if ((keepW[i >> 5] >> (i & 31)) & 1u) {
            if (c < 4)        val = (&cbox4[i].x)[c];
            else if (c == 4)  val = tops[i];
            else              val = tcls[i];
        }
        ob[e] = val;
    }
}

// ---------------------------------------------------------------------------
extern "C" void kernel_launch(void* const* d_in, const int* in_sizes, int n_in,
                              void* d_out, int out_size, void* d_ws, size_t ws_size,
                              hipStream_t stream) {
    const float* p3 = (const float*)d_in[0];
    const float* p4 = (const float*)d_in[1];
    const float* p5 = (const float*)d_in[2];
    float* out = (float*)d_out;

    float* scores = (float*)d_ws;                                  // B*A f32
    int*   cls    = (int*)(scores + (size_t)BATCH * A_TOT);        // B*A i32

    score_kernel<<<4200, 256, 0, stream>>>(p3, p4, p5, scores, cls);
    nms_kernel<<<BATCH, 1024, 0, stream>>>(p3, p4, p5, scores, cls, out);
}